// Round 1
// baseline (358.141 us; speedup 1.0000x reference)
//
#include <hip/hip_runtime.h>

#define KPAD 736   // 726 padded to 23*32
#define FPAD 744   // feat LDS row stride (bf16), breaks bank conflicts
#define BM 32      // edges per block

typedef short bfrag8 __attribute__((ext_vector_type(8)));
typedef float f32x4 __attribute__((ext_vector_type(4)));

__device__ __forceinline__ unsigned short f2bf(float f) {
  union { float f; unsigned u; } v; v.f = f;
  unsigned r = v.u + 0x7fffu + ((v.u >> 16) & 1u);
  return (unsigned short)(r >> 16);
}

// ---- prep: transpose+pad weights to bf16 (N-major, K contiguous), zero counters ----
__global__ void prep_weights(const float* __restrict__ cW1, const float* __restrict__ nW1,
                             const float* __restrict__ cW2, const float* __restrict__ nW2,
                             unsigned short* __restrict__ w1tc, unsigned short* __restrict__ w1tn,
                             unsigned short* __restrict__ w2tc, unsigned short* __restrict__ w2tn,
                             int* __restrict__ cnt) {
  int i = blockIdx.x * blockDim.x + threadIdx.x;
  if (i == 0) { cnt[0] = 0; cnt[1] = 0; }
  const int T0 = 192 * KPAD, T1 = 128 * KPAD, T2 = 128 * 192, T3 = 128 * 128;
  const int tot = T0 + T1 + T2 + T3;
  for (; i < tot; i += gridDim.x * blockDim.x) {
    int idx = i;
    if (idx < T0) {
      int n = idx / KPAD, k = idx - n * KPAD;
      w1tc[idx] = f2bf(k < 726 ? cW1[k * 192 + n] : 0.f);
    } else if ((idx -= T0) < T1) {
      int n = idx / KPAD, k = idx - n * KPAD;
      w1tn[idx] = f2bf(k < 726 ? nW1[k * 128 + n] : 0.f);
    } else if ((idx -= T1) < T2) {
      int n = idx / 192, k = idx - n * 192;
      w2tc[idx] = f2bf(cW2[k * 128 + n]);
    } else {
      idx -= T2;
      int n = idx >> 7, k = idx & 127;
      w2tn[idx] = f2bf(nW2[k * 128 + n]);
    }
  }
}

// ---- compaction: per-type edge lists ----
__global__ void compact_edges(const int* __restrict__ et, int* __restrict__ cnt,
                              int* __restrict__ l0, int* __restrict__ l1,
                              float* __restrict__ out, int n) {
  int i = blockIdx.x * blockDim.x + threadIdx.x;
  for (; i < n; i += gridDim.x * blockDim.x) {
    int ty = et[i];
    if (ty == 0)      l0[atomicAdd(&cnt[0], 1)] = i;
    else if (ty == 1) l1[atomicAdd(&cnt[1], 1)] = i;
    else {
      // reference emits zeros for unknown types; write them every call
      float4 z = make_float4(0.f, 0.f, 0.f, 0.f);
      float4* po = (float4*)(out + (size_t)i * 128);
      #pragma unroll
      for (int j = 0; j < 32; ++j) po[j] = z;
    }
  }
}

// ---- main fused kernel: feat build -> GEMM1 -> LN/ReLU -> GEMM2 -> store ----
template <int CH>
__global__ __launch_bounds__(256, 2)
void edge_mlp(const float* __restrict__ h_nodes,
              const float* __restrict__ edge_scalars,
              const int* __restrict__ edge_src, const int* __restrict__ edge_dst,
              const int* __restrict__ edge_type,
              const int* __restrict__ ct_src, const int* __restrict__ ct_dst,
              const int* __restrict__ pr_src, const int* __restrict__ pr_dst,
              const float* __restrict__ emb_et, const float* __restrict__ emb_ct,
              const float* __restrict__ emb_pr,
              const unsigned short* __restrict__ w1t, const unsigned short* __restrict__ w2t,
              const float* __restrict__ b1, const float* __restrict__ g,
              const float* __restrict__ beta, const float* __restrict__ b2,
              const int* __restrict__ cntp, const int* __restrict__ list,
              float* __restrict__ out) {
  constexpr int NF = CH / 64;   // N-fragments per wave in GEMM1 (3 or 2)
  constexpr int NW = CH / 4;    // per-wave N span (48 or 32)
  union SA {
    unsigned short feat[BM][FPAD]; // phase 1-2
    float h[BM][200];              // phase 3-4
    float ot[BM][132];             // phase 6
  };
  __shared__ SA sA;
  __shared__ unsigned short sHb[BM][200];

  const int c = cntp[0];
  const int base = blockIdx.x * BM;
  if (base >= c) return;
  const int m_cnt = min(BM, c - base);

  const int t = threadIdx.x;
  const int lane = t & 63;
  const int wid = t >> 6;
  const int r = t >> 3;   // 0..31 row
  const int l8 = t & 7;   // 8 threads per row
  const int d0 = l8 * 16;

  const int eid = (r < m_cnt) ? list[base + r] : -1;

  // ---- Phase 1: build bf16 feature tile in LDS ----
  if (eid >= 0) {
    const int su = edge_src[eid], dv = edge_dst[eid];
    const float4* pu = (const float4*)(h_nodes + (size_t)su * 128 + d0);
    const float4* pv = (const float4*)(h_nodes + (size_t)dv * 128 + d0);
    #pragma unroll
    for (int cidx = 0; cidx < 4; ++cidx) {
      float4 u = pu[cidx], v = pv[cidx];
      float ua[4] = {u.x, u.y, u.z, u.w}, va[4] = {v.x, v.y, v.z, v.w};
      #pragma unroll
      for (int j = 0; j < 4; ++j) {
        int d = d0 + cidx * 4 + j;
        float a = ua[j], bb = va[j];
        sA.feat[r][d]       = f2bf(a);
        sA.feat[r][128 + d] = f2bf(bb);
        sA.feat[r][256 + d] = f2bf(a * bb);
        sA.feat[r][384 + d] = f2bf(fabsf(a - bb));
        sA.feat[r][512 + d] = f2bf(bb - a);
      }
    }
    int et = edge_type[eid], cs = ct_src[eid], cd = ct_dst[eid];
    int ps = pr_src[eid], pd = pr_dst[eid];
    et = (et >= 0 && et < 2) ? et : 0;
    cs = (cs >= 0 && cs < 256) ? cs : 0;
    cd = (cd >= 0 && cd < 256) ? cd : 0;
    ps = (ps >= 0 && ps < 64) ? ps : 0;
    pd = (pd >= 0 && pd < 64) ? pd : 0;
    #pragma unroll
    for (int j = 0; j < 13; ++j) {
      int idx = 640 + l8 * 13 + j;
      float v;
      if      (idx < 656) v = emb_et[et * 16 + (idx - 640)];
      else if (idx < 672) v = emb_ct[cs * 16 + (idx - 656)];
      else if (idx < 688) v = emb_ct[cd * 16 + (idx - 672)];
      else if (idx < 704) v = emb_pr[ps * 16 + (idx - 688)];
      else if (idx < 720) v = emb_pr[pd * 16 + (idx - 704)];
      else if (idx < 726) v = fminf(fmaxf(edge_scalars[(size_t)eid * 6 + (idx - 720)], -10.f), 10.f);
      else v = 0.f;
      sA.feat[r][idx] = f2bf(v);
    }
  } else {
    #pragma unroll
    for (int j = 0; j < 16; ++j) {
      int d = d0 + j;
      sA.feat[r][d] = 0; sA.feat[r][128 + d] = 0; sA.feat[r][256 + d] = 0;
      sA.feat[r][384 + d] = 0; sA.feat[r][512 + d] = 0;
    }
    #pragma unroll
    for (int j = 0; j < 13; ++j) sA.feat[r][640 + l8 * 13 + j] = 0;
  }
  __syncthreads();

  // ---- Phase 2: GEMM1  H = feat @ W1 ----
  const int lrow = lane & 15;
  const int khalf = (lane >> 4) * 8;
  const int nbase = wid * NW;

  f32x4 acc[2][NF];
  #pragma unroll
  for (int mf = 0; mf < 2; ++mf)
    #pragma unroll
    for (int nf = 0; nf < NF; ++nf) acc[mf][nf] = 0;

  for (int k0 = 0; k0 < KPAD; k0 += 32) {
    bfrag8 a0 = *(const bfrag8*)&sA.feat[lrow][k0 + khalf];
    bfrag8 a1 = *(const bfrag8*)&sA.feat[16 + lrow][k0 + khalf];
    #pragma unroll
    for (int nf = 0; nf < NF; ++nf) {
      bfrag8 bf = *(const bfrag8*)&w1t[(size_t)(nbase + nf * 16 + lrow) * KPAD + k0 + khalf];
      acc[0][nf] = __builtin_amdgcn_mfma_f32_16x16x32_bf16(a0, bf, acc[0][nf], 0, 0, 0);
      acc[1][nf] = __builtin_amdgcn_mfma_f32_16x16x32_bf16(a1, bf, acc[1][nf], 0, 0, 0);
    }
  }
  __syncthreads();  // feat no longer needed; safe to overwrite with H

  // ---- Phase 3: H + b1 -> LDS fp32 ----
  const int mrow = (lane >> 4) * 4;
  #pragma unroll
  for (int nf = 0; nf < NF; ++nf) {
    int n = nbase + nf * 16 + lrow;
    float b1v = b1[n];
    #pragma unroll
    for (int mf = 0; mf < 2; ++mf)
      #pragma unroll
      for (int rg = 0; rg < 4; ++rg)
        sA.h[mf * 16 + mrow + rg][n] = acc[mf][nf][rg] + b1v;
  }
  __syncthreads();

  // ---- Phase 4: LayerNorm + ReLU -> bf16 LDS ----
  {
    constexpr int PER = CH / 8;
    float vals[PER];
    float sum = 0.f, sq = 0.f;
    #pragma unroll
    for (int i = 0; i < PER; ++i) {
      float v = sA.h[r][l8 + 8 * i];
      vals[i] = v; sum += v; sq += v * v;
    }
    sum += __shfl_xor(sum, 1); sq += __shfl_xor(sq, 1);
    sum += __shfl_xor(sum, 2); sq += __shfl_xor(sq, 2);
    sum += __shfl_xor(sum, 4); sq += __shfl_xor(sq, 4);
    const float inv = 1.f / (float)CH;
    float mu = sum * inv;
    float var = fmaxf(sq * inv - mu * mu, 0.f);
    float rs = rsqrtf(var + 1e-5f);
    #pragma unroll
    for (int i = 0; i < PER; ++i) {
      int n = l8 + 8 * i;
      float v = (vals[i] - mu) * rs * g[n] + beta[n];
      sHb[r][n] = f2bf(fmaxf(v, 0.f));
    }
  }
  __syncthreads();

  // ---- Phase 5: GEMM2  O = relu(LN(H)) @ W2 ----
  const int n2 = wid * 32;
  f32x4 acc2[2][2];
  #pragma unroll
  for (int mf = 0; mf < 2; ++mf) { acc2[mf][0] = 0; acc2[mf][1] = 0; }
  #pragma unroll
  for (int k0 = 0; k0 < CH; k0 += 32) {
    bfrag8 a0 = *(const bfrag8*)&sHb[lrow][k0 + khalf];
    bfrag8 a1 = *(const bfrag8*)&sHb[16 + lrow][k0 + khalf];
    #pragma unroll
    for (int nf = 0; nf < 2; ++nf) {
      bfrag8 bf = *(const bfrag8*)&w2t[(size_t)(n2 + nf * 16 + lrow) * CH + k0 + khalf];
      acc2[0][nf] = __builtin_amdgcn_mfma_f32_16x16x32_bf16(a0, bf, acc2[0][nf], 0, 0, 0);
      acc2[1][nf] = __builtin_amdgcn_mfma_f32_16x16x32_bf16(a1, bf, acc2[1][nf], 0, 0, 0);
    }
  }

  // ---- Phase 6: out tile + b2 -> LDS, then coalesced store ----
  #pragma unroll
  for (int nf = 0; nf < 2; ++nf) {
    int n = n2 + nf * 16 + lrow;
    float b2v = b2[n];
    #pragma unroll
    for (int mf = 0; mf < 2; ++mf)
      #pragma unroll
      for (int rg = 0; rg < 4; ++rg)
        sA.ot[mf * 16 + mrow + rg][n] = acc2[mf][nf][rg] + b2v;
  }
  __syncthreads();

  if (eid >= 0) {
    float4* po = (float4*)(out + (size_t)eid * 128 + d0);
    const float4* ps = (const float4*)&sA.ot[r][d0];
    #pragma unroll
    for (int j = 0; j < 4; ++j) po[j] = ps[j];
  }
}

extern "C" void kernel_launch(void* const* d_in, const int* in_sizes, int n_in,
                              void* d_out, int out_size, void* d_ws, size_t ws_size,
                              hipStream_t stream) {
  (void)n_in; (void)out_size; (void)ws_size;
  const float* h_nodes      = (const float*)d_in[0];
  const float* edge_scalars = (const float*)d_in[1];
  const int*   edge_src     = (const int*)d_in[2];
  const int*   edge_dst     = (const int*)d_in[3];
  const int*   edge_type    = (const int*)d_in[4];
  const int*   ct_s         = (const int*)d_in[5];
  const int*   ct_d         = (const int*)d_in[6];
  const int*   pr_s         = (const int*)d_in[7];
  const int*   pr_d         = (const int*)d_in[8];
  const float* emb_et       = (const float*)d_in[9];
  const float* emb_ct       = (const float*)d_in[10];
  const float* emb_pr       = (const float*)d_in[11];
  const float* cW1  = (const float*)d_in[12];
  const float* cb1  = (const float*)d_in[13];
  const float* cg   = (const float*)d_in[14];
  const float* cbe  = (const float*)d_in[15];
  const float* cW2  = (const float*)d_in[16];
  const float* cb2  = (const float*)d_in[17];
  const float* nW1  = (const float*)d_in[18];
  const float* nb1  = (const float*)d_in[19];
  const float* ng   = (const float*)d_in[20];
  const float* nbe  = (const float*)d_in[21];
  const float* nW2  = (const float*)d_in[22];
  const float* nb2  = (const float*)d_in[23];
  const int n_edges = in_sizes[2];
  float* out = (float*)d_out;

  // workspace layout
  char* ws = (char*)d_ws;
  int* cnt   = (int*)ws;                 // 2 counters
  int* list0 = (int*)(ws + 256);
  int* list1 = list0 + n_edges;
  size_t woff = (256 + (size_t)2 * n_edges * sizeof(int) + 255) & ~(size_t)255;
  unsigned short* w1tc = (unsigned short*)(ws + woff);
  unsigned short* w1tn = w1tc + 192 * KPAD;
  unsigned short* w2tc = w1tn + 128 * KPAD;
  unsigned short* w2tn = w2tc + 128 * 192;

  prep_weights<<<1080, 256, 0, stream>>>(cW1, nW1, cW2, nW2, w1tc, w1tn, w2tc, w2tn, cnt);
  compact_edges<<<(n_edges + 255) / 256, 256, 0, stream>>>(edge_type, cnt, list0, list1, out, n_edges);

  const int nb = (n_edges + BM - 1) / BM;
  edge_mlp<192><<<nb, 256, 0, stream>>>(h_nodes, edge_scalars, edge_src, edge_dst, edge_type,
                                        ct_s, ct_d, pr_s, pr_d, emb_et, emb_ct, emb_pr,
                                        w1tc, w2tc, cb1, cg, cbe, cb2, cnt + 0, list0, out);
  edge_mlp<128><<<nb, 256, 0, stream>>>(h_nodes, edge_scalars, edge_src, edge_dst, edge_type,
                                        ct_s, ct_d, pr_s, pr_d, emb_et, emb_ct, emb_pr,
                                        w1tn, w2tn, nb1, ng, nbe, nb2, cnt + 1, list1, out);
}

// Round 2
// 254.478 us; speedup vs baseline: 1.4074x; 1.4074x over previous
//
#include <hip/hip_runtime.h>

#define KPAD 736   // 726 padded to 23*32
#define KS   23    // KPAD/32
#define FPAD 744   // feat LDS row stride (bf16)
#define BM   32    // edges per block

typedef short bfrag8 __attribute__((ext_vector_type(8)));
typedef float f32x4 __attribute__((ext_vector_type(4)));

__device__ __forceinline__ unsigned short f2bf(float f) {
  union { float f; unsigned u; } v; v.f = f;
  unsigned r = v.u + 0x7fffu + ((v.u >> 16) & 1u);
  return (unsigned short)(r >> 16);
}
__device__ __forceinline__ unsigned pk2(float a, float b) {
  return (unsigned)f2bf(a) | ((unsigned)f2bf(b) << 16);
}

struct SmemP2 {
  unsigned short hb[BM][200];   // 12800 B : relu(LN(H)) bf16
  float red[4][BM][2];          // 1024 B  : per-wave partial sum/sumsq
  float mu[BM];                 // 128 B
  float rs[BM];                 // 128 B
  float ot[BM][132];            // 16896 B : output staging
};
struct alignas(16) Smem {
  union {
    unsigned short feat[BM][FPAD];  // 47616 B (phase 1-2)
    SmemP2 p2;                      // 30976 B (phase 3+)
  } u;
};

// ---- prep: weights -> fragment-major bf16 (contiguous 1KB per n16 x k32 MFMA tile) ----
__global__ void prep_weights(const float* __restrict__ cW1, const float* __restrict__ nW1,
                             const float* __restrict__ cW2, const float* __restrict__ nW2,
                             unsigned short* __restrict__ w1c, unsigned short* __restrict__ w1n,
                             unsigned short* __restrict__ w2c, unsigned short* __restrict__ w2n,
                             int* __restrict__ cnt) {
  int i = blockIdx.x * blockDim.x + threadIdx.x;
  if (i == 0) { cnt[0] = 0; cnt[1] = 0; }
  const int T0 = 12 * KS * 512, T1 = 8 * KS * 512, T2 = 8 * 6 * 512, T3 = 8 * 4 * 512;
  const int tot = T0 + T1 + T2 + T3;
  for (; i < tot; i += gridDim.x * blockDim.x) {
    int idx = i;
    const float* src; unsigned short* dst; int N, Kreal, KSm, rel;
    if (idx < T0)              { src = cW1; dst = w1c; N = 192; Kreal = 726; KSm = KS; rel = idx; }
    else if ((idx -= T0) < T1) { src = nW1; dst = w1n; N = 128; Kreal = 726; KSm = KS; rel = idx; }
    else if ((idx -= T1) < T2) { src = cW2; dst = w2c; N = 128; Kreal = 192; KSm = 6;  rel = idx; }
    else { idx -= T2;            src = nW2; dst = w2n; N = 128; Kreal = 128; KSm = 4;  rel = idx; }
    int blk = rel >> 9, within = rel & 511;
    int l = within >> 3, e = within & 7;
    int n16 = blk / KSm, k32 = blk - n16 * KSm;
    int n = n16 * 16 + (l & 15);
    int k = k32 * 32 + ((l >> 4) * 8) + e;
    dst[rel] = f2bf(k < Kreal ? src[(size_t)k * N + n] : 0.f);
  }
}

// ---- compaction: per-type edge lists ----
__global__ void compact_edges(const int* __restrict__ et, int* __restrict__ cnt,
                              int* __restrict__ l0, int* __restrict__ l1,
                              float* __restrict__ out, int n) {
  int i = blockIdx.x * blockDim.x + threadIdx.x;
  for (; i < n; i += gridDim.x * blockDim.x) {
    int ty = et[i];
    if (ty == 0)      l0[atomicAdd(&cnt[0], 1)] = i;
    else if (ty == 1) l1[atomicAdd(&cnt[1], 1)] = i;
    else {
      float4 z = make_float4(0.f, 0.f, 0.f, 0.f);
      float4* po = (float4*)(out + (size_t)i * 128);
      #pragma unroll
      for (int j = 0; j < 32; ++j) po[j] = z;
    }
  }
}

template <int CH>
__device__ __forceinline__ void mlp_tile(
    Smem& sm, int tile, int c, const int* __restrict__ list,
    const float* __restrict__ h_nodes, const float* __restrict__ edge_scalars,
    const int* __restrict__ esrc, const int* __restrict__ edst,
    const int* __restrict__ et_, const int* __restrict__ cts, const int* __restrict__ ctd,
    const int* __restrict__ prs, const int* __restrict__ prd,
    const float* __restrict__ emb_et, const float* __restrict__ emb_ct, const float* __restrict__ emb_pr,
    const unsigned short* __restrict__ w1f, const unsigned short* __restrict__ w2f,
    const float* __restrict__ b1, const float* __restrict__ g,
    const float* __restrict__ beta, const float* __restrict__ b2,
    float* __restrict__ out)
{
  constexpr int NF  = CH / 64;   // GEMM1 N-fragments per wave (3 or 2)
  constexpr int KS2 = CH / 32;   // GEMM2 K-steps (6 or 4)
  const int t    = threadIdx.x;
  const int lane = t & 63;
  const int wid  = t >> 6;
  const int base = tile * BM;
  const int lrow = lane & 15;
  const int kq   = (lane >> 4) * 8;

  // prefetch per-lane bias/gain early (L2-resident, hides latency under gather phase)
  float b1v[NF], gv[NF], bev[NF];
  #pragma unroll
  for (int nf = 0; nf < NF; ++nf) {
    int n = wid * (NF * 16) + nf * 16 + lrow;
    b1v[nf] = b1[n]; gv[nf] = g[n]; bev[nf] = beta[n];
  }
  float b2v[2];
  #pragma unroll
  for (int nf = 0; nf < 2; ++nf) b2v[nf] = b2[wid * 32 + nf * 16 + lrow];

  // ---- Phase 1a: gather u,v (coalesced per row) -> 5 derived segs, packed 8B LDS writes ----
  {
    const int r = t >> 3, l8 = t & 7;
    const int eid = (base + r < c) ? list[base + r] : -1;
    if (eid >= 0) {
      const float* bu = h_nodes + (size_t)esrc[eid] * 128;
      const float* bv = h_nodes + (size_t)edst[eid] * 128;
      #pragma unroll
      for (int j = 0; j < 4; ++j) {
        const int d = (l8 + 8 * j) * 4;
        float4 uu = *(const float4*)(bu + d);
        float4 vv = *(const float4*)(bv + d);
        float ua[4] = {uu.x, uu.y, uu.z, uu.w};
        float va[4] = {vv.x, vv.y, vv.z, vv.w};
        uint2 w0 = make_uint2(pk2(ua[0], ua[1]), pk2(ua[2], ua[3]));
        uint2 w1_ = make_uint2(pk2(va[0], va[1]), pk2(va[2], va[3]));
        uint2 w2_ = make_uint2(pk2(ua[0] * va[0], ua[1] * va[1]), pk2(ua[2] * va[2], ua[3] * va[3]));
        uint2 w3_ = make_uint2(pk2(fabsf(ua[0] - va[0]), fabsf(ua[1] - va[1])),
                               pk2(fabsf(ua[2] - va[2]), fabsf(ua[3] - va[3])));
        uint2 w4_ = make_uint2(pk2(va[0] - ua[0], va[1] - ua[1]), pk2(va[2] - ua[2], va[3] - ua[3]));
        *(uint2*)&sm.u.feat[r][0 * 128 + d] = w0;
        *(uint2*)&sm.u.feat[r][1 * 128 + d] = w1_;
        *(uint2*)&sm.u.feat[r][2 * 128 + d] = w2_;
        *(uint2*)&sm.u.feat[r][3 * 128 + d] = w3_;
        *(uint2*)&sm.u.feat[r][4 * 128 + d] = w4_;
      }
    } else {
      uint2 z = make_uint2(0u, 0u);
      #pragma unroll
      for (int j = 0; j < 4; ++j) {
        const int d = (l8 + 8 * j) * 4;
        #pragma unroll
        for (int s = 0; s < 5; ++s) *(uint2*)&sm.u.feat[r][s * 128 + d] = z;
      }
    }
  }
  // ---- Phase 1b: embeddings + scalars (<=2-way divergence, 12 independent gathers) ----
  {
    const int rb = t & 31, eb = t >> 5;
    const int eid = (base + rb < c) ? list[base + rb] : -1;
    if (eid >= 0) {
      int i0 = et_[eid]; i0 = ((unsigned)i0 < 2u)   ? i0 : 0;
      int i1 = cts[eid]; i1 = ((unsigned)i1 < 256u) ? i1 : 0;
      int i2 = ctd[eid]; i2 = ((unsigned)i2 < 256u) ? i2 : 0;
      int i3 = prs[eid]; i3 = ((unsigned)i3 < 64u)  ? i3 : 0;
      int i4 = prd[eid]; i4 = ((unsigned)i4 < 64u)  ? i4 : 0;
      const float* tp0 = emb_et + i0 * 16;
      const float* tp1 = emb_ct + i1 * 16;
      const float* tp2 = emb_ct + i2 * 16;
      const float* tp3 = emb_pr + i3 * 16;
      const float* tp4 = emb_pr + i4 * 16;
      const float* tp5 = edge_scalars + (size_t)eid * 6;
      #pragma unroll
      for (int j = 0; j < 12; ++j) {
        int e = eb * 12 + j;
        int tbl = e >> 4, off = e & 15;
        float v;
        if      (tbl == 0) v = tp0[off];
        else if (tbl == 1) v = tp1[off];
        else if (tbl == 2) v = tp2[off];
        else if (tbl == 3) v = tp3[off];
        else if (tbl == 4) v = tp4[off];
        else v = (off < 6) ? fminf(fmaxf(tp5[off < 6 ? off : 0], -10.f), 10.f) : 0.f;
        sm.u.feat[rb][640 + e] = f2bf(v);
      }
    } else {
      #pragma unroll
      for (int j = 0; j < 12; ++j) sm.u.feat[rb][640 + eb * 12 + j] = 0;
    }
  }
  __syncthreads();

  // ---- Phase 2: GEMM1, B prefetched one K-step ahead (fragment-major contiguous loads) ----
  f32x4 acc[2][NF];
  #pragma unroll
  for (int mf = 0; mf < 2; ++mf)
    #pragma unroll
    for (int nf = 0; nf < NF; ++nf) acc[mf][nf] = 0;

  const char* wb = (const char*)w1f + ((size_t)(wid * NF) * KS) * 1024 + (size_t)lane * 16;
  bfrag8 bc[NF];
  #pragma unroll
  for (int nf = 0; nf < NF; ++nf) bc[nf] = *(const bfrag8*)(wb + (size_t)nf * KS * 1024);
  #pragma unroll
  for (int k32 = 1; k32 < KS; ++k32) {
    bfrag8 bn[NF];
    #pragma unroll
    for (int nf = 0; nf < NF; ++nf)
      bn[nf] = *(const bfrag8*)(wb + ((size_t)nf * KS + k32) * 1024);
    bfrag8 a0 = *(const bfrag8*)&sm.u.feat[lrow][(k32 - 1) * 32 + kq];
    bfrag8 a1 = *(const bfrag8*)&sm.u.feat[16 + lrow][(k32 - 1) * 32 + kq];
    #pragma unroll
    for (int nf = 0; nf < NF; ++nf) {
      acc[0][nf] = __builtin_amdgcn_mfma_f32_16x16x32_bf16(a0, bc[nf], acc[0][nf], 0, 0, 0);
      acc[1][nf] = __builtin_amdgcn_mfma_f32_16x16x32_bf16(a1, bc[nf], acc[1][nf], 0, 0, 0);
    }
    #pragma unroll
    for (int nf = 0; nf < NF; ++nf) bc[nf] = bn[nf];
  }
  {
    bfrag8 a0 = *(const bfrag8*)&sm.u.feat[lrow][(KS - 1) * 32 + kq];
    bfrag8 a1 = *(const bfrag8*)&sm.u.feat[16 + lrow][(KS - 1) * 32 + kq];
    #pragma unroll
    for (int nf = 0; nf < NF; ++nf) {
      acc[0][nf] = __builtin_amdgcn_mfma_f32_16x16x32_bf16(a0, bc[nf], acc[0][nf], 0, 0, 0);
      acc[1][nf] = __builtin_amdgcn_mfma_f32_16x16x32_bf16(a1, bc[nf], acc[1][nf], 0, 0, 0);
    }
  }
  __syncthreads();   // feat dead; p2 overlay becomes safe

  // ---- Phase 3: bias fold + in-register row reduction (16-lane shuffle) ----
  float sum_[2][4], sq_[2][4];
  #pragma unroll
  for (int mf = 0; mf < 2; ++mf)
    #pragma unroll
    for (int rg = 0; rg < 4; ++rg) {
      float s = 0.f, q = 0.f;
      #pragma unroll
      for (int nf = 0; nf < NF; ++nf) {
        float val = acc[mf][nf][rg] + b1v[nf];
        acc[mf][nf][rg] = val;
        s += val; q += val * val;
      }
      sum_[mf][rg] = s; sq_[mf][rg] = q;
    }
  #pragma unroll
  for (int d = 1; d < 16; d <<= 1) {
    #pragma unroll
    for (int mf = 0; mf < 2; ++mf)
      #pragma unroll
      for (int rg = 0; rg < 4; ++rg) {
        sum_[mf][rg] += __shfl_xor(sum_[mf][rg], d);
        sq_[mf][rg]  += __shfl_xor(sq_[mf][rg], d);
      }
  }
  if (lrow == 0) {
    const int half = lane >> 4;
    #pragma unroll
    for (int mf = 0; mf < 2; ++mf)
      #pragma unroll
      for (int rg = 0; rg < 4; ++rg) {
        int row = mf * 16 + half * 4 + rg;
        sm.u.p2.red[wid][row][0] = sum_[mf][rg];
        sm.u.p2.red[wid][row][1] = sq_[mf][rg];
      }
  }
  __syncthreads();
  if (t < BM) {
    float ss = sm.u.p2.red[0][t][0] + sm.u.p2.red[1][t][0] + sm.u.p2.red[2][t][0] + sm.u.p2.red[3][t][0];
    float qq = sm.u.p2.red[0][t][1] + sm.u.p2.red[1][t][1] + sm.u.p2.red[2][t][1] + sm.u.p2.red[3][t][1];
    float muv = ss * (1.f / CH);
    float var = fmaxf(qq * (1.f / CH) - muv * muv, 0.f);
    sm.u.p2.mu[t] = muv;
    sm.u.p2.rs[t] = rsqrtf(var + 1e-5f);
  }
  __syncthreads();

  // ---- Phase 4: normalize + relu + bf16 -> hb ----
  #pragma unroll
  for (int mf = 0; mf < 2; ++mf)
    #pragma unroll
    for (int rg = 0; rg < 4; ++rg) {
      int row = mf * 16 + (lane >> 4) * 4 + rg;
      float muv = sm.u.p2.mu[row], rsv = sm.u.p2.rs[row];
      #pragma unroll
      for (int nf = 0; nf < NF; ++nf) {
        float v = (acc[mf][nf][rg] - muv) * rsv * gv[nf] + bev[nf];
        sm.u.p2.hb[row][wid * (NF * 16) + nf * 16 + lrow] = f2bf(fmaxf(v, 0.f));
      }
    }
  __syncthreads();

  // ---- Phase 5: GEMM2 (B prefetched) ----
  f32x4 acc2[2][2];
  #pragma unroll
  for (int mf = 0; mf < 2; ++mf) { acc2[mf][0] = 0; acc2[mf][1] = 0; }
  const char* wb2 = (const char*)w2f + ((size_t)(wid * 2) * KS2) * 1024 + (size_t)lane * 16;
  bfrag8 c0 = *(const bfrag8*)(wb2);
  bfrag8 c1 = *(const bfrag8*)(wb2 + (size_t)KS2 * 1024);
  #pragma unroll
  for (int k32 = 1; k32 < KS2; ++k32) {
    bfrag8 n0 = *(const bfrag8*)(wb2 + (size_t)k32 * 1024);
    bfrag8 n1 = *(const bfrag8*)(wb2 + ((size_t)KS2 + k32) * 1024);
    bfrag8 a0 = *(const bfrag8*)&sm.u.p2.hb[lrow][(k32 - 1) * 32 + kq];
    bfrag8 a1 = *(const bfrag8*)&sm.u.p2.hb[16 + lrow][(k32 - 1) * 32 + kq];
    acc2[0][0] = __builtin_amdgcn_mfma_f32_16x16x32_bf16(a0, c0, acc2[0][0], 0, 0, 0);
    acc2[1][0] = __builtin_amdgcn_mfma_f32_16x16x32_bf16(a1, c0, acc2[1][0], 0, 0, 0);
    acc2[0][1] = __builtin_amdgcn_mfma_f32_16x16x32_bf16(a0, c1, acc2[0][1], 0, 0, 0);
    acc2[1][1] = __builtin_amdgcn_mfma_f32_16x16x32_bf16(a1, c1, acc2[1][1], 0, 0, 0);
    c0 = n0; c1 = n1;
  }
  {
    bfrag8 a0 = *(const bfrag8*)&sm.u.p2.hb[lrow][(KS2 - 1) * 32 + kq];
    bfrag8 a1 = *(const bfrag8*)&sm.u.p2.hb[16 + lrow][(KS2 - 1) * 32 + kq];
    acc2[0][0] = __builtin_amdgcn_mfma_f32_16x16x32_bf16(a0, c0, acc2[0][0], 0, 0, 0);
    acc2[1][0] = __builtin_amdgcn_mfma_f32_16x16x32_bf16(a1, c0, acc2[1][0], 0, 0, 0);
    acc2[0][1] = __builtin_amdgcn_mfma_f32_16x16x32_bf16(a0, c1, acc2[0][1], 0, 0, 0);
    acc2[1][1] = __builtin_amdgcn_mfma_f32_16x16x32_bf16(a1, c1, acc2[1][1], 0, 0, 0);
  }

  // ---- Phase 6: + b2 -> ot (disjoint from hb, no barrier needed before) ----
  #pragma unroll
  for (int nf2 = 0; nf2 < 2; ++nf2) {
    int n = wid * 32 + nf2 * 16 + lrow;
    float bb = b2v[nf2];
    #pragma unroll
    for (int mf = 0; mf < 2; ++mf)
      #pragma unroll
      for (int rg = 0; rg < 4; ++rg)
        sm.u.p2.ot[mf * 16 + (lane >> 4) * 4 + rg][n] = acc2[mf][nf2][rg] + bb;
  }
  __syncthreads();

  {
    const int r = t >> 3, l8 = t & 7;
    const int eid = (base + r < c) ? list[base + r] : -1;
    if (eid >= 0) {
      float4* po = (float4*)(out + (size_t)eid * 128 + l8 * 16);
      const float4* ps = (const float4*)&sm.u.p2.ot[r][l8 * 16];
      #pragma unroll
      for (int j = 0; j < 4; ++j) po[j] = ps[j];
    }
  }
}

struct Args {
  const float *h_nodes, *edge_scalars;
  const int *esrc, *edst, *et, *cts, *ctd, *prs, *prd;
  const float *emb_et, *emb_ct, *emb_pr;
  const unsigned short *w1c, *w2c;
  const float *cb1, *cg, *cbe, *cb2;
  const unsigned short *w1n, *w2n;
  const float *nb1, *ng, *nbe, *nb2;
  const int *cnt, *l0, *l1;
  float* out;
};

__global__ __launch_bounds__(256, 3) void edge_mlp_all(Args A) {
  __shared__ Smem sm;
  const int c0 = A.cnt[0];
  const int nb0 = (c0 + BM - 1) / BM;
  const int b = blockIdx.x;
  if (b < nb0) {
    mlp_tile<192>(sm, b, c0, A.l0, A.h_nodes, A.edge_scalars, A.esrc, A.edst, A.et,
                  A.cts, A.ctd, A.prs, A.prd, A.emb_et, A.emb_ct, A.emb_pr,
                  A.w1c, A.w2c, A.cb1, A.cg, A.cbe, A.cb2, A.out);
  } else {
    const int c1 = A.cnt[1];
    const int t2 = b - nb0;
    if (t2 * BM < c1)
      mlp_tile<128>(sm, t2, c1, A.l1, A.h_nodes, A.edge_scalars, A.esrc, A.edst, A.et,
                    A.cts, A.ctd, A.prs, A.prd, A.emb_et, A.emb_ct, A.emb_pr,
                    A.w1n, A.w2n, A.nb1, A.ng, A.nbe, A.nb2, A.out);
  }
}

extern "C" void kernel_launch(void* const* d_in, const int* in_sizes, int n_in,
                              void* d_out, int out_size, void* d_ws, size_t ws_size,
                              hipStream_t stream) {
  (void)n_in; (void)out_size; (void)ws_size;
  const float* h_nodes      = (const float*)d_in[0];
  const float* edge_scalars = (const float*)d_in[1];
  const int*   edge_src     = (const int*)d_in[2];
  const int*   edge_dst     = (const int*)d_in[3];
  const int*   edge_type    = (const int*)d_in[4];
  const int*   ct_s         = (const int*)d_in[5];
  const int*   ct_d         = (const int*)d_in[6];
  const int*   pr_s         = (const int*)d_in[7];
  const int*   pr_d         = (const int*)d_in[8];
  const float* emb_et       = (const float*)d_in[9];
  const float* emb_ct       = (const float*)d_in[10];
  const float* emb_pr       = (const float*)d_in[11];
  const float* cW1 = (const float*)d_in[12];
  const float* cb1 = (const float*)d_in[13];
  const float* cg  = (const float*)d_in[14];
  const float* cbe = (const float*)d_in[15];
  const float* cW2 = (const float*)d_in[16];
  const float* cb2 = (const float*)d_in[17];
  const float* nW1 = (const float*)d_in[18];
  const float* nb1 = (const float*)d_in[19];
  const float* ng  = (const float*)d_in[20];
  const float* nbe = (const float*)d_in[21];
  const float* nW2 = (const float*)d_in[22];
  const float* nb2 = (const float*)d_in[23];
  const int n_edges = in_sizes[2];
  float* out = (float*)d_out;

  char* ws = (char*)d_ws;
  int* cnt   = (int*)ws;
  int* list0 = (int*)(ws + 256);
  int* list1 = list0 + n_edges;
  size_t woff = (256 + (size_t)2 * n_edges * sizeof(int) + 255) & ~(size_t)255;
  unsigned short* w1c = (unsigned short*)(ws + woff);
  unsigned short* w1n = w1c + 12 * KS * 512;
  unsigned short* w2c = w1n + 8 * KS * 512;
  unsigned short* w2n = w2c + 8 * 6 * 512;

  prep_weights<<<1080, 256, 0, stream>>>(cW1, nW1, cW2, nW2, w1c, w1n, w2c, w2n, cnt);
  compact_edges<<<(n_edges + 255) / 256, 256, 0, stream>>>(edge_type, cnt, list0, list1, out, n_edges);

  Args A;
  A.h_nodes = h_nodes; A.edge_scalars = edge_scalars;
  A.esrc = edge_src; A.edst = edge_dst; A.et = edge_type;
  A.cts = ct_s; A.ctd = ct_d; A.prs = pr_s; A.prd = pr_d;
  A.emb_et = emb_et; A.emb_ct = emb_ct; A.emb_pr = emb_pr;
  A.w1c = w1c; A.w2c = w2c; A.cb1 = cb1; A.cg = cg; A.cbe = cbe; A.cb2 = cb2;
  A.w1n = w1n; A.w2n = w2n; A.nb1 = nb1; A.ng = ng; A.nbe = nbe; A.nb2 = nb2;
  A.cnt = cnt; A.l0 = list0; A.l1 = list1; A.out = out;

  const int nbAll = (n_edges + BM - 1) / BM + 2;
  edge_mlp_all<<<nbAll, 256, 0, stream>>>(A);
}